// Round 5
// baseline (486.178 us; speedup 1.0000x reference)
//
#include <hip/hip_runtime.h>

#define N_NODES  131072
#define G_GRAPHS 1024
#define NPG0     128
#define HDIM     128
#define E_EDGES  2097152
#define EPG      2048
#define BN_EPS   1e-5f
#define INV_SQRT2 0.70710678118654752440f

typedef __attribute__((ext_vector_type(8))) short bf16x8;
typedef __attribute__((ext_vector_type(4))) float f32x4;

__device__ __forceinline__ float bf2f(ushort u) {
  union { unsigned int i; float f; } v; v.i = ((unsigned int)u) << 16; return v.f;
}
__device__ __forceinline__ ushort f2bf(float f) {
  union { float f; unsigned int i; } v; v.f = f;
  unsigned int u = v.i;
  return (ushort)((u + 0x7FFFu + ((u >> 16) & 1u)) >> 16);
}

// async global->LDS DMA, 16B per lane (wave-uniform LDS base + lane*16)
__device__ __forceinline__ void ldsdma16(const void* g, void* l) {
  __builtin_amdgcn_global_load_lds(
      (const __attribute__((address_space(1))) void*)g,
      (__attribute__((address_space(3))) void*)l, 16, 0, 0);
}

__device__ __forceinline__ void bn_coefs(const float* __restrict__ stats,
                                         const float* __restrict__ gamma,
                                         const float* __restrict__ beta,
                                         float inv_n, float* cA, float* cC, int t) {
  if (t < HDIM) {
    float s  = stats[t];
    float ss = stats[HDIM + t];
    float m  = s * inv_n;
    float var = fmaxf(ss * inv_n - m * m, 0.f);
    float a = gamma[t] * rsqrtf(var + BN_EPS);
    cA[t] = a;
    cC[t] = beta[t] - m * a;
  }
}

// column stats for 4 consecutive channels held per-lane (swapped-D layout):
// reduce over the 16 lr lanes (rows), leader does LDS atomics.
__device__ __forceinline__ void colstat4(float* __restrict__ sred, int c0,
                                         const float y[4], int lr) {
  float s0 = y[0], s1 = y[1], s2 = y[2], s3 = y[3];
  float q0 = y[0]*y[0], q1 = y[1]*y[1], q2 = y[2]*y[2], q3 = y[3]*y[3];
  #pragma unroll
  for (int m = 1; m <= 8; m <<= 1) {
    s0 += __shfl_xor(s0, m); s1 += __shfl_xor(s1, m);
    s2 += __shfl_xor(s2, m); s3 += __shfl_xor(s3, m);
    q0 += __shfl_xor(q0, m); q1 += __shfl_xor(q1, m);
    q2 += __shfl_xor(q2, m); q3 += __shfl_xor(q3, m);
  }
  if (lr == 0) {
    atomicAdd(&sred[c0 + 0], s0); atomicAdd(&sred[HDIM + c0 + 0], q0);
    atomicAdd(&sred[c0 + 1], s1); atomicAdd(&sred[HDIM + c0 + 1], q1);
    atomicAdd(&sred[c0 + 2], s2); atomicAdd(&sred[HDIM + c0 + 2], q2);
    atomicAdd(&sred[c0 + 3], s3); atomicAdd(&sred[HDIM + c0 + 3], q3);
  }
}

// Transpose + bf16-convert the 7 weight matrices into wt[m][n][k].
__global__ __launch_bounds__(256, 2)
void k_prep(const float* __restrict__ w_lin_start, const float* __restrict__ w_conv1,
            const float* __restrict__ w_conv2, ushort* __restrict__ wt) {
  __shared__ ushort T[128 * 136];
  const int m = blockIdx.x;
  const int t = threadIdx.x;
  const float* W = (m == 0) ? w_lin_start
                 : (m <= 3) ? w_conv1 + (size_t)(m - 1) * HDIM * HDIM
                            : w_conv2 + (size_t)(m - 4) * HDIM * HDIM;
  for (int it = 0; it < 64; ++it) {
    int idx = it * 256 + t;          // W row-major [k][n]
    int k = idx >> 7, n = idx & 127;
    T[k * 136 + n] = f2bf(W[idx]);
  }
  __syncthreads();
  ushort* o = wt + (size_t)m * HDIM * HDIM;  // [n][k]
  for (int it = 0; it < 64; ++it) {
    int idx = it * 256 + t;
    int n = idx >> 7, k = idx & 127;
    o[idx] = T[k * 136 + n];
  }
}

// GEMM: out = (act(in) @ W) + bias ; col stats -> outStats.
// 512 thr = 8 waves x 16 rows. Swapped-operand MFMA: D gives each lane its
// row (lr) with 4 consecutive channels per fragment -> coalesced ushort4 stores.
template <int ACT, int FP32IN>
__global__ __launch_bounds__(512, 4)
void k_mm(const void* __restrict__ in_v, ushort* __restrict__ out,
          const ushort* __restrict__ Wt, const float* __restrict__ bias,
          const float* __restrict__ actStats, const float* __restrict__ actG,
          const float* __restrict__ actB, float act_inv_n,
          float* __restrict__ outStats) {
  __shared__ ushort At[HDIM * HDIM];   // [row][swchunk*8]
  __shared__ ushort Bt[HDIM * HDIM];   // [col][swchunk*8]
  __shared__ float biasL[HDIM];
  __shared__ float sred[2 * HDIM];
  __shared__ float aA[HDIM], aC[HDIM];
  const int t = threadIdx.x;
  const int lane = t & 63;
  const int w = t >> 6;
  const int lr = lane & 15;
  const int lg = lane >> 4;

  // B staging via LDS-DMA (pre-swizzled global source, linear LDS dest)
  #pragma unroll
  for (int is = 0; is < 4; ++is) {
    const int col = is * 32 + w * 4 + (lane >> 4);
    const int sc  = lane & 15;
    const int gsc = sc ^ (col & 7);
    ldsdma16(Wt + (size_t)col * HDIM + gsc * 8, &Bt[(is * 512 + w * 64) * 8]);
  }

  if (ACT) bn_coefs(actStats, actG, actB, act_inv_n, aA, aC, t);
  if (t < HDIM) biasL[t] = bias[t];
  if (t < 2 * HDIM) sred[t] = 0.f;
  if (ACT) __syncthreads();

  const size_t blkRow0 = (size_t)blockIdx.x * 128;
  const float*  inF = (const float*)in_v;
  const ushort* inB = (const ushort*)in_v;
  #pragma unroll
  for (int is = 0; is < 4; ++is) {
    const int cid = is * 512 + t;
    const int row = cid >> 4, sc = cid & 15;
    bf16x8 a;
    if (FP32IN) {
      const float* gp = inF + (blkRow0 + row) * HDIM + sc * 8;
      float4 v0 = *(const float4*)gp;
      float4 v1 = *(const float4*)(gp + 4);
      a[0] = (short)f2bf(v0.x); a[1] = (short)f2bf(v0.y);
      a[2] = (short)f2bf(v0.z); a[3] = (short)f2bf(v0.w);
      a[4] = (short)f2bf(v1.x); a[5] = (short)f2bf(v1.y);
      a[6] = (short)f2bf(v1.z); a[7] = (short)f2bf(v1.w);
    } else {
      a = *(const bf16x8*)(inB + (blkRow0 + row) * HDIM + sc * 8);
      if (ACT) {
        const int k0 = sc * 8;
        #pragma unroll
        for (int j = 0; j < 8; ++j) {
          float f = fmaxf(fmaf(aA[k0 + j], bf2f((ushort)a[j]), aC[k0 + j]), 0.f);
          a[j] = (short)f2bf(f);
        }
      }
    }
    *(bf16x8*)&At[row * HDIM + (sc ^ (row & 7)) * 8] = a;
  }
  __syncthreads();

  f32x4 acc[8];
  #pragma unroll
  for (int cf = 0; cf < 8; ++cf) acc[cf] = (f32x4){0.f, 0.f, 0.f, 0.f};

  const int rowL = w * 16 + lr;
  #pragma unroll
  for (int ks = 0; ks < 4; ++ks) {
    const int c = ks * 4 + lg;
    const int swc = c ^ (lr & 7);
    bf16x8 afr = *(const bf16x8*)&At[rowL * HDIM + swc * 8];
    #pragma unroll
    for (int cf = 0; cf < 8; ++cf) {
      const int col = cf * 16 + lr;
      bf16x8 bfr = *(const bf16x8*)&Bt[col * HDIM + swc * 8];
      // swapped: A-slot = W frag, B-slot = x frag
      acc[cf] = __builtin_amdgcn_mfma_f32_16x16x32_bf16(bfr, afr, acc[cf], 0, 0, 0);
    }
  }

  // epilogue: lane holds row (blkRow0+w*16+lr), channels cf*16+lg*4+0..3
  const size_t grow = blkRow0 + w * 16 + lr;
  #pragma unroll
  for (int cf = 0; cf < 8; ++cf) {
    const int c0 = cf * 16 + lg * 4;
    float y[4];
    #pragma unroll
    for (int r = 0; r < 4; ++r) y[r] = acc[cf][r] + biasL[c0 + r];
    ushort4 st;
    st.x = f2bf(y[0]); st.y = f2bf(y[1]); st.z = f2bf(y[2]); st.w = f2bf(y[3]);
    *(ushort4*)&out[grow * HDIM + c0] = st;
    colstat4(sred, c0, y, lr);
  }
  __syncthreads();
  if (t < 2 * HDIM) atomicAdd(&outStats[t], sred[t]);
}

// Fused GIN aggregation + GEMM(w1): out = (act(x) + sum_{src->dst} act(x)) @ W1 + b1.
// Block = 128-row tile = GPB graphs. x staged f32 in LDS with per-row XOR chunk
// swizzle (bank-conflict-free for both staging writes and per-thread agg reads).
// Thread (w,lr,lg) owns tile row w*16+lr, channels ks*32+lg*8..+7 == exactly its
// MFMA B-fragment -> aggregate straight into registers, then MFMA with W1 (LDS).
template <int GPB, int ACT>
__global__ __launch_bounds__(512, 2)
void k_aggmm(const ushort* __restrict__ xin, ushort* __restrict__ out,
             const int* __restrict__ esrc, const int* __restrict__ edst,
             int shift, const ushort* __restrict__ Wt,
             const float* __restrict__ bias,
             const float* __restrict__ actStats, const float* __restrict__ actG,
             const float* __restrict__ actB, float act_inv_n,
             float* __restrict__ outStats) {
  constexpr int EPB = EPG * GPB;     // edges per block
  constexpr int EPT = EPB / 512;     // 4 / 8 / 16
  __shared__ float  xs[128 * HDIM];  // 64 KB, chunk-swizzled
  __shared__ ushort WtL[HDIM * HDIM];
  __shared__ int    srcs[EPB];
  __shared__ int    cnt[128], off2[128], cur[128], scn[128];
  __shared__ float  biasL[HDIM], sred[2 * HDIM], aA[HDIM], aC[HDIM];
  const int t = threadIdx.x;
  const int lane = t & 63;
  const int w = t >> 6;
  const int lr = lane & 15;
  const int lg = lane >> 4;
  const int blk = blockIdx.x;

  // W1 -> LDS DMA (drains at first barrier)
  #pragma unroll
  for (int is = 0; is < 4; ++is) {
    const int col = is * 32 + w * 4 + (lane >> 4);
    const int gsc = (lane & 15) ^ (col & 7);
    ldsdma16(Wt + (size_t)col * HDIM + gsc * 8, &WtL[(is * 512 + w * 64) * 8]);
  }

  // edge list -> regs (tile-row local ids)
  int myd[EPT], mys[EPT];
  const int ebase = blk * EPB;
  #pragma unroll
  for (int u = 0; u < EPT; ++u) {
    const int e = ebase + t + u * 512;
    myd[u] = (edst[e] >> shift) - blk * 128;
    mys[u] = (esrc[e] >> shift) - blk * 128;
  }

  if (ACT) bn_coefs(actStats, actG, actB, act_inv_n, aA, aC, t);
  if (t < HDIM) biasL[t] = bias[t];
  if (t < 2 * HDIM) sred[t] = 0.f;
  if (t < 128) { cnt[t] = 0; cur[t] = 0; }
  __syncthreads();

  // stage x -> xs f32 (one float4 per thread-iter: conflict-free), + ACT
  float4* xs4 = (float4*)xs;
  const ushort* xg = xin + (size_t)blk * 128 * HDIM;
  #pragma unroll
  for (int it = 0; it < 8; ++it) {
    const int idx = it * 512 + t;          // float4 id 0..4095
    const int row = idx >> 5, c4 = idx & 31;
    ushort4 v = *(const ushort4*)(xg + (size_t)row * HDIM + c4 * 4);
    float4 f;
    f.x = bf2f(v.x); f.y = bf2f(v.y); f.z = bf2f(v.z); f.w = bf2f(v.w);
    if (ACT) {
      const int c = c4 * 4;
      f.x = fmaxf(fmaf(aA[c + 0], f.x, aC[c + 0]), 0.f);
      f.y = fmaxf(fmaf(aA[c + 1], f.y, aC[c + 1]), 0.f);
      f.z = fmaxf(fmaf(aA[c + 2], f.z, aC[c + 2]), 0.f);
      f.w = fmaxf(fmaf(aA[c + 3], f.w, aC[c + 3]), 0.f);
    }
    xs4[row * 32 + (c4 ^ ((row & 7) << 2))] = f;
  }
  #pragma unroll
  for (int u = 0; u < EPT; ++u) atomicAdd(&cnt[myd[u]], 1);
  __syncthreads();

  // exclusive scan of cnt -> off2
  if (t < 128) scn[t] = cnt[t];
  __syncthreads();
  #pragma unroll
  for (int s = 1; s < 128; s <<= 1) {
    int v = (t < 128 && t >= s) ? scn[t - s] : 0;
    __syncthreads();
    if (t < 128) scn[t] += v;
    __syncthreads();
  }
  if (t < 128) off2[t] = scn[t] - cnt[t];
  __syncthreads();

  #pragma unroll
  for (int u = 0; u < EPT; ++u) {
    int p = off2[myd[u]] + atomicAdd(&cur[myd[u]], 1);
    srcs[p] = mys[u];
  }
  __syncthreads();

  // aggregate: myrow's channels ks*32+lg*8..+7 into registers
  const int myrow = w * 16 + lr;
  float4 hacc[4][2];
  {
    const int msw = (myrow & 7) << 2;
    #pragma unroll
    for (int ks = 0; ks < 4; ++ks) {
      hacc[ks][0] = xs4[myrow * 32 + ((ks * 8 + lg * 2 + 0) ^ msw)];
      hacc[ks][1] = xs4[myrow * 32 + ((ks * 8 + lg * 2 + 1) ^ msw)];
    }
  }
  {
    const int o = off2[myrow], c2 = cnt[myrow];
    for (int e = 0; e < c2; ++e) {
      const int s = srcs[o + e];
      const int ssw = (s & 7) << 2;
      #pragma unroll
      for (int ks = 0; ks < 4; ++ks) {
        float4 v0 = xs4[s * 32 + ((ks * 8 + lg * 2 + 0) ^ ssw)];
        float4 v1 = xs4[s * 32 + ((ks * 8 + lg * 2 + 1) ^ ssw)];
        hacc[ks][0].x += v0.x; hacc[ks][0].y += v0.y;
        hacc[ks][0].z += v0.z; hacc[ks][0].w += v0.w;
        hacc[ks][1].x += v1.x; hacc[ks][1].y += v1.y;
        hacc[ks][1].z += v1.z; hacc[ks][1].w += v1.w;
      }
    }
  }

  // h -> bf16 B-fragments
  bf16x8 xf[4];
  #pragma unroll
  for (int ks = 0; ks < 4; ++ks) {
    xf[ks][0] = (short)f2bf(hacc[ks][0].x); xf[ks][1] = (short)f2bf(hacc[ks][0].y);
    xf[ks][2] = (short)f2bf(hacc[ks][0].z); xf[ks][3] = (short)f2bf(hacc[ks][0].w);
    xf[ks][4] = (short)f2bf(hacc[ks][1].x); xf[ks][5] = (short)f2bf(hacc[ks][1].y);
    xf[ks][6] = (short)f2bf(hacc[ks][1].z); xf[ks][7] = (short)f2bf(hacc[ks][1].w);
  }

  // MFMA with W1 (swapped operands)
  f32x4 acc[8];
  #pragma unroll
  for (int cf = 0; cf < 8; ++cf) acc[cf] = (f32x4){0.f, 0.f, 0.f, 0.f};
  #pragma unroll
  for (int ks = 0; ks < 4; ++ks) {
    const int kb = ks * 4 + lg;
    const int swc = kb ^ (lr & 7);
    #pragma unroll
    for (int cf = 0; cf < 8; ++cf) {
      const int col = cf * 16 + lr;
      bf16x8 wf = *(const bf16x8*)&WtL[col * HDIM + swc * 8];
      acc[cf] = __builtin_amdgcn_mfma_f32_16x16x32_bf16(wf, xf[ks], acc[cf], 0, 0, 0);
    }
  }

  // epilogue
  const size_t grow = (size_t)blk * 128 + myrow;
  #pragma unroll
  for (int cf = 0; cf < 8; ++cf) {
    const int c0 = cf * 16 + lg * 4;
    float y[4];
    #pragma unroll
    for (int r = 0; r < 4; ++r) y[r] = acc[cf][r] + biasL[c0 + r];
    ushort4 st;
    st.x = f2bf(y[0]); st.y = f2bf(y[1]); st.z = f2bf(y[2]); st.w = f2bf(y[3]);
    *(ushort4*)&out[grow * HDIM + c0] = st;
    colstat4(sred, c0, y, lr);
  }
  __syncthreads();
  if (t < 2 * HDIM) atomicAdd(&outStats[t], sred[t]);
}

// x' = haar(act(h)) ; emb[g] ; embd col-stats. bf16 in/out, emb f32.
__global__ __launch_bounds__(256, 4)
void k_pool(const ushort* __restrict__ hin, ushort* __restrict__ xout,
            float* __restrict__ emb, int layer, int npg_in,
            const float* __restrict__ actStats, const float* __restrict__ actG,
            const float* __restrict__ actB, float act_inv_n,
            float* __restrict__ embStats) {
  __shared__ float aA[HDIM], aC[HDIM];
  __shared__ float red[256];
  const int t = threadIdx.x;
  const int g = blockIdx.x;
  bn_coefs(actStats, actG, actB, act_inv_n, aA, aC, t);
  __syncthreads();
  const int c = t & 127;
  const int ph = t >> 7;
  const int npg_out = npg_in >> 1;
  const ushort* hb = hin + (size_t)g * npg_in * HDIM;
  ushort* xb = xout + (size_t)g * npg_out * HDIM;
  const float a = aA[c], cc = aC[c];
  float es = 0.f;
  for (int p = ph; p < npg_out; p += 2) {
    float v0 = fmaxf(fmaf(a, bf2f(hb[(2 * p    ) * HDIM + c]), cc), 0.f);
    float v1 = fmaxf(fmaf(a, bf2f(hb[(2 * p + 1) * HDIM + c]), cc), 0.f);
    float xv = (v0 + v1) * INV_SQRT2;
    xb[p * HDIM + c] = f2bf(xv);
    es += xv;
  }
  red[t] = es;
  __syncthreads();
  if (t < HDIM) {
    float e = red[t] + red[t + HDIM];
    emb[(size_t)g * 384 + layer * HDIM + t] = e;
    atomicAdd(&embStats[t], e);
    atomicAdd(&embStats[HDIM + t], e * e);
  }
}

__global__ __launch_bounds__(128, 8)
void k_final(const float* __restrict__ emb,
             const float* __restrict__ se0, const float* __restrict__ se1,
             const float* __restrict__ se2,
             const float* __restrict__ bneG, const float* __restrict__ bneB,
             const float* __restrict__ linW, const float* __restrict__ linB,
             float* __restrict__ outp) {
  __shared__ float ev[384];
  __shared__ float eA[384], eC[384];
  const int t = threadIdx.x;
  const int g = blockIdx.x;
  if (t < 128) {
    const float* se[3] = {se0, se1, se2};
    const float inv_n = 1.f / (float)G_GRAPHS;
    #pragma unroll
    for (int l = 0; l < 3; ++l) {
      float s  = se[l][t];
      float ss = se[l][128 + t];
      float m  = s * inv_n;
      float var = fmaxf(ss * inv_n - m * m, 0.f);
      float a = bneG[l * 128 + t] * rsqrtf(var + BN_EPS);
      eA[l * 128 + t] = a;
      eC[l * 128 + t] = bneB[l * 128 + t] - m * a;
    }
  }
  __syncthreads();
  for (int j = t; j < 384; j += 128)
    ev[j] = fmaxf(fmaf(eA[j], emb[(size_t)g * 384 + j], eC[j]), 0.f);
  __syncthreads();
  if (t < 10) {
    float acc = linB[t];
    #pragma unroll 8
    for (int j = 0; j < 384; ++j) acc += ev[j] * linW[j * 10 + t];
    outp[g * 10 + t] = acc;
  }
}

extern "C" void kernel_launch(void* const* d_in, const int* in_sizes, int n_in,
                              void* d_out, int out_size, void* d_ws, size_t ws_size,
                              hipStream_t stream) {
  const float* x           = (const float*)d_in[0];
  const int*   ei          = (const int*)  d_in[1];
  const float* lin_start_w = (const float*)d_in[2];
  const float* lin_start_b = (const float*)d_in[3];
  const float* bn_start_g  = (const float*)d_in[4];
  const float* bn_start_b  = (const float*)d_in[5];
  const float* conv_w1     = (const float*)d_in[6];
  const float* conv_b1     = (const float*)d_in[7];
  const float* conv_bn_g   = (const float*)d_in[8];
  const float* conv_bn_b   = (const float*)d_in[9];
  const float* conv_w2     = (const float*)d_in[10];
  const float* conv_b2     = (const float*)d_in[11];
  const float* bn_g        = (const float*)d_in[12];
  const float* bn_b        = (const float*)d_in[13];
  const float* bne_g       = (const float*)d_in[14];
  const float* bne_b       = (const float*)d_in[15];
  const float* lin_w       = (const float*)d_in[16];
  const float* lin_b       = (const float*)d_in[17];
  float* outp = (float*)d_out;

  const size_t NH = (size_t)N_NODES * HDIM;
  float*  stats = (float*)d_ws;                       // 10 slots * 256
  float*  emb   = stats + 10 * 256;                   // G * 384
  ushort* wt    = (ushort*)(emb + (size_t)G_GRAPHS * 384);  // 7 * 128 * 128
  ushort* bufA  = wt + 7 * HDIM * HDIM;
  ushort* bufB  = bufA + NH;

  hipMemsetAsync(stats, 0, 10 * 256 * sizeof(float), stream);

  const int* esrc = ei;
  const int* edst = ei + E_EDGES;

  k_prep<<<7, 256, 0, stream>>>(lin_start_w, conv_w1, conv_w2, wt);

  // y0 = x @ lin_start_w + b (stats -> slot 0)
  k_mm<0, 1><<<N_NODES / 128, 512, 0, stream>>>(
      x, bufA, wt, lin_start_b, nullptr, nullptr, nullptr, 0.f, stats);

  ushort* cur = bufA;
  ushort* alt = bufB;
  for (int i = 0; i < 3; ++i) {
    const int n = N_NODES >> i;
    const float inv_n = 1.f / (float)n;
    float* s1 = stats + (1 + 3 * i) * 256;
    float* s2 = stats + (2 + 3 * i) * 256;
    float* se = stats + (3 + 3 * i) * 256;
    const ushort* wt1 = wt + (size_t)(1 + i) * HDIM * HDIM;
    const ushort* wt2 = wt + (size_t)(4 + i) * HDIM * HDIM;

    // h1 = (act(x) + agg(act(x))) @ w1 + b1  (stats -> s1)
    if (i == 0)
      k_aggmm<1, 1><<<n / 128, 512, 0, stream>>>(cur, alt, esrc, edst, 0, wt1,
          conv_b1 + i * HDIM, stats, bn_start_g, bn_start_b,
          1.f / (float)N_NODES, s1);
    else if (i == 1)
      k_aggmm<2, 0><<<n / 128, 512, 0, stream>>>(cur, alt, esrc, edst, 1, wt1,
          conv_b1 + i * HDIM, nullptr, nullptr, nullptr, 0.f, s1);
    else
      k_aggmm<4, 0><<<n / 128, 512, 0, stream>>>(cur, alt, esrc, edst, 2, wt1,
          conv_b1 + i * HDIM, nullptr, nullptr, nullptr, 0.f, s1);

    // h2 = relu(bn(h1)) @ w2 + b2 (stats -> s2)
    k_mm<1, 0><<<n / 128, 512, 0, stream>>>(
        alt, cur, wt2, conv_b2 + i * HDIM,
        s1, conv_bn_g + i * HDIM, conv_bn_b + i * HDIM, inv_n, s2);
    // x' = haar(relu(bn(h2))) ; emb col i ; embd stats -> se
    k_pool<<<G_GRAPHS, 256, 0, stream>>>(
        cur, alt, emb, i, NPG0 >> i,
        s2, bn_g + i * HDIM, bn_b + i * HDIM, inv_n, se);

    ushort* tmp = cur; cur = alt; alt = tmp;
  }

  k_final<<<G_GRAPHS, 128, 0, stream>>>(
      emb, stats + 3 * 256, stats + 6 * 256, stats + 9 * 256,
      bne_g, bne_b, lin_w, lin_b, outp);
}

// Round 6
// 392.230 us; speedup vs baseline: 1.2395x; 1.2395x over previous
//
#include <hip/hip_runtime.h>

#define N_NODES  131072
#define G_GRAPHS 1024
#define NPG0     128
#define HDIM     128
#define E_EDGES  2097152
#define EPG      2048
#define BN_EPS   1e-5f
#define INV_SQRT2 0.70710678118654752440f

typedef __attribute__((ext_vector_type(8))) short bf16x8;
typedef __attribute__((ext_vector_type(4))) float f32x4;

__device__ __forceinline__ float bf2f(ushort u) {
  union { unsigned int i; float f; } v; v.i = ((unsigned int)u) << 16; return v.f;
}
__device__ __forceinline__ ushort f2bf(float f) {
  union { float f; unsigned int i; } v; v.f = f;
  unsigned int u = v.i;
  return (ushort)((u + 0x7FFFu + ((u >> 16) & 1u)) >> 16);
}

// async global->LDS DMA, 16B per lane (wave-uniform LDS base + lane*16)
__device__ __forceinline__ void ldsdma16(const void* g, void* l) {
  __builtin_amdgcn_global_load_lds(
      (const __attribute__((address_space(1))) void*)g,
      (__attribute__((address_space(3))) void*)l, 16, 0, 0);
}

__device__ __forceinline__ void bn_coefs(const float* __restrict__ stats,
                                         const float* __restrict__ gamma,
                                         const float* __restrict__ beta,
                                         float inv_n, float* cA, float* cC, int t) {
  if (t < HDIM) {
    float s  = stats[t];
    float ss = stats[HDIM + t];
    float m  = s * inv_n;
    float var = fmaxf(ss * inv_n - m * m, 0.f);
    float a = gamma[t] * rsqrtf(var + BN_EPS);
    cA[t] = a;
    cC[t] = beta[t] - m * a;
  }
}

// column stats for 4 consecutive channels held per-lane (lane=row layout):
// reduce over the 16 lr lanes (rows), leader does LDS atomics.
__device__ __forceinline__ void colstat4(float* __restrict__ sred, int c0,
                                         const float y[4], int lr) {
  float s0 = y[0], s1 = y[1], s2 = y[2], s3 = y[3];
  float q0 = y[0]*y[0], q1 = y[1]*y[1], q2 = y[2]*y[2], q3 = y[3]*y[3];
  #pragma unroll
  for (int m = 1; m <= 8; m <<= 1) {
    s0 += __shfl_xor(s0, m); s1 += __shfl_xor(s1, m);
    s2 += __shfl_xor(s2, m); s3 += __shfl_xor(s3, m);
    q0 += __shfl_xor(q0, m); q1 += __shfl_xor(q1, m);
    q2 += __shfl_xor(q2, m); q3 += __shfl_xor(q3, m);
  }
  if (lr == 0) {
    atomicAdd(&sred[c0 + 0], s0); atomicAdd(&sred[HDIM + c0 + 0], q0);
    atomicAdd(&sred[c0 + 1], s1); atomicAdd(&sred[HDIM + c0 + 1], q1);
    atomicAdd(&sred[c0 + 2], s2); atomicAdd(&sred[HDIM + c0 + 2], q2);
    atomicAdd(&sred[c0 + 3], s3); atomicAdd(&sred[HDIM + c0 + 3], q3);
  }
}

// Transpose + bf16-convert the 7 weight matrices into wt[m][n][k].
__global__ __launch_bounds__(256, 2)
void k_prep(const float* __restrict__ w_lin_start, const float* __restrict__ w_conv1,
            const float* __restrict__ w_conv2, ushort* __restrict__ wt) {
  __shared__ ushort T[128 * 136];
  const int m = blockIdx.x;
  const int t = threadIdx.x;
  const float* W = (m == 0) ? w_lin_start
                 : (m <= 3) ? w_conv1 + (size_t)(m - 1) * HDIM * HDIM
                            : w_conv2 + (size_t)(m - 4) * HDIM * HDIM;
  for (int it = 0; it < 64; ++it) {
    int idx = it * 256 + t;          // W row-major [k][n]
    int k = idx >> 7, n = idx & 127;
    T[k * 136 + n] = f2bf(W[idx]);
  }
  __syncthreads();
  ushort* o = wt + (size_t)m * HDIM * HDIM;  // [n][k]
  for (int it = 0; it < 64; ++it) {
    int idx = it * 256 + t;
    int n = idx >> 7, k = idx & 127;
    o[idx] = T[k * 136 + n];
  }
}

// GEMM: out = (act(in) @ W) + bias ; col stats -> outStats.
// 512 thr = 8 waves x 16 rows. Swapped-operand MFMA: lane=row, 4-ch ushort4 stores.
template <int ACT, int FP32IN>
__global__ __launch_bounds__(512, 4)
void k_mm(const void* __restrict__ in_v, ushort* __restrict__ out,
          const ushort* __restrict__ Wt, const float* __restrict__ bias,
          const float* __restrict__ actStats, const float* __restrict__ actG,
          const float* __restrict__ actB, float act_inv_n,
          float* __restrict__ outStats) {
  __shared__ ushort At[HDIM * HDIM];   // [row][swchunk*8]
  __shared__ ushort Bt[HDIM * HDIM];   // [col][swchunk*8]
  __shared__ float biasL[HDIM];
  __shared__ float sred[2 * HDIM];
  __shared__ float aA[HDIM], aC[HDIM];
  const int t = threadIdx.x;
  const int lane = t & 63;
  const int w = t >> 6;
  const int lr = lane & 15;
  const int lg = lane >> 4;

  #pragma unroll
  for (int is = 0; is < 4; ++is) {
    const int col = is * 32 + w * 4 + (lane >> 4);
    const int sc  = lane & 15;
    const int gsc = sc ^ (col & 7);
    ldsdma16(Wt + (size_t)col * HDIM + gsc * 8, &Bt[(is * 512 + w * 64) * 8]);
  }

  if (ACT) bn_coefs(actStats, actG, actB, act_inv_n, aA, aC, t);
  if (t < HDIM) biasL[t] = bias[t];
  if (t < 2 * HDIM) sred[t] = 0.f;
  if (ACT) __syncthreads();

  const size_t blkRow0 = (size_t)blockIdx.x * 128;
  const float*  inF = (const float*)in_v;
  const ushort* inB = (const ushort*)in_v;
  #pragma unroll
  for (int is = 0; is < 4; ++is) {
    const int cid = is * 512 + t;
    const int row = cid >> 4, sc = cid & 15;
    bf16x8 a;
    if (FP32IN) {
      const float* gp = inF + (blkRow0 + row) * HDIM + sc * 8;
      float4 v0 = *(const float4*)gp;
      float4 v1 = *(const float4*)(gp + 4);
      a[0] = (short)f2bf(v0.x); a[1] = (short)f2bf(v0.y);
      a[2] = (short)f2bf(v0.z); a[3] = (short)f2bf(v0.w);
      a[4] = (short)f2bf(v1.x); a[5] = (short)f2bf(v1.y);
      a[6] = (short)f2bf(v1.z); a[7] = (short)f2bf(v1.w);
    } else {
      a = *(const bf16x8*)(inB + (blkRow0 + row) * HDIM + sc * 8);
      if (ACT) {
        const int k0 = sc * 8;
        #pragma unroll
        for (int j = 0; j < 8; ++j) {
          float f = fmaxf(fmaf(aA[k0 + j], bf2f((ushort)a[j]), aC[k0 + j]), 0.f);
          a[j] = (short)f2bf(f);
        }
      }
    }
    *(bf16x8*)&At[row * HDIM + (sc ^ (row & 7)) * 8] = a;
  }
  __syncthreads();

  f32x4 acc[8];
  #pragma unroll
  for (int cf = 0; cf < 8; ++cf) acc[cf] = (f32x4){0.f, 0.f, 0.f, 0.f};

  const int rowL = w * 16 + lr;
  #pragma unroll
  for (int ks = 0; ks < 4; ++ks) {
    const int c = ks * 4 + lg;
    const int swc = c ^ (lr & 7);
    bf16x8 afr = *(const bf16x8*)&At[rowL * HDIM + swc * 8];
    #pragma unroll
    for (int cf = 0; cf < 8; ++cf) {
      const int col = cf * 16 + lr;
      bf16x8 bfr = *(const bf16x8*)&Bt[col * HDIM + swc * 8];
      acc[cf] = __builtin_amdgcn_mfma_f32_16x16x32_bf16(bfr, afr, acc[cf], 0, 0, 0);
    }
  }

  const size_t grow = blkRow0 + w * 16 + lr;
  #pragma unroll
  for (int cf = 0; cf < 8; ++cf) {
    const int c0 = cf * 16 + lg * 4;
    float y[4];
    #pragma unroll
    for (int r = 0; r < 4; ++r) y[r] = acc[cf][r] + biasL[c0 + r];
    ushort4 st;
    st.x = f2bf(y[0]); st.y = f2bf(y[1]); st.z = f2bf(y[2]); st.w = f2bf(y[3]);
    *(ushort4*)&out[grow * HDIM + c0] = st;
    colstat4(sred, c0, y, lr);
  }
  __syncthreads();
  if (t < 2 * HDIM) atomicAdd(&outStats[t], sred[t]);
}

// Fused GIN front: out = (I+M) @ (act(x) @ W1) + b1, where M[dst][src] = edge
// multiplicity (block-diag per graph; 128-row tile covers whole graphs).
// Two chained MFMAs; M built as u8 counts in LDS via atomics. LDS reuse:
// AtM = act(x) tile, then M; BtYt = W1, then Y^T (granule-XOR swizzled).
template <int EPT, int ACT>
__global__ __launch_bounds__(512, 4)
void k_gin(const ushort* __restrict__ xin, ushort* __restrict__ out,
           const int* __restrict__ esrc, const int* __restrict__ edst,
           int shift, const ushort* __restrict__ Wt,
           const float* __restrict__ bias,
           const float* __restrict__ actStats, const float* __restrict__ actG,
           const float* __restrict__ actB, float act_inv_n,
           float* __restrict__ outStats) {
  __shared__ ushort AtM[HDIM * HDIM];   // 32 KB: act(x) tile -> M u8[128][128]
  __shared__ ushort BtYt[HDIM * HDIM];  // 32 KB: W1 -> Y^T
  __shared__ float biasL[HDIM], sred[2 * HDIM], aA[HDIM], aC[HDIM];
  const int t = threadIdx.x;
  const int lane = t & 63;
  const int w = t >> 6;
  const int lr = lane & 15;
  const int lg = lane >> 4;
  const int blk = blockIdx.x;

  // W1 -> BtYt via DMA (pre-swizzled source, linear LDS dest)
  #pragma unroll
  for (int is = 0; is < 4; ++is) {
    const int col = is * 32 + w * 4 + (lane >> 4);
    const int gsc = (lane & 15) ^ (col & 7);
    ldsdma16(Wt + (size_t)col * HDIM + gsc * 8, &BtYt[(is * 512 + w * 64) * 8]);
  }

  if (ACT) bn_coefs(actStats, actG, actB, act_inv_n, aA, aC, t);
  if (t < HDIM) biasL[t] = bias[t];
  if (t < 2 * HDIM) sred[t] = 0.f;
  if (ACT) __syncthreads();

  // stage act(x) -> AtM (row-chunk XOR swizzle, same as k_mm)
  const size_t blkRow0 = (size_t)blk * 128;
  const ushort* xg = xin + blkRow0 * HDIM;
  #pragma unroll
  for (int is = 0; is < 4; ++is) {
    const int cid = is * 512 + t;
    const int row = cid >> 4, sc = cid & 15;
    bf16x8 a = *(const bf16x8*)(xg + (size_t)row * HDIM + sc * 8);
    if (ACT) {
      const int k0 = sc * 8;
      #pragma unroll
      for (int j = 0; j < 8; ++j) {
        float f = fmaxf(fmaf(aA[k0 + j], bf2f((ushort)a[j]), aC[k0 + j]), 0.f);
        a[j] = (short)f2bf(f);
      }
    }
    *(bf16x8*)&AtM[row * HDIM + (sc ^ (row & 7)) * 8] = a;
  }
  __syncthreads();                       // (1) At + W1 ready

  // x fragments for this thread's row -> registers; then At is dead
  const int myrow = w * 16 + lr;
  bf16x8 xf[4];
  #pragma unroll
  for (int ks = 0; ks < 4; ++ks)
    xf[ks] = *(const bf16x8*)&AtM[myrow * HDIM + ((ks * 4 + lg) ^ (lr & 7)) * 8];
  __syncthreads();                       // (2) all xf loaded

  // memset M (u8[128][128] over At space)
  uint* Mw = (uint*)AtM;
  #pragma unroll
  for (int i = 0; i < 8; ++i) Mw[i * 512 + t] = 0u;
  __syncthreads();                       // (2b) M zeroed

  // build M: diag (self term) + edge multiplicities, src-granule XOR swizzle
  if (t < 128) {
    const int g = (t >> 3) ^ (t & 15);
    const int b = t * 128 + g * 8 + (t & 7);
    atomicAdd(&Mw[b >> 2], 1u << ((b & 3) * 8));
  }
  {
    const int ebase = blk * (EPT * 512);
    #pragma unroll
    for (int u = 0; u < EPT; ++u) {
      const int e = ebase + t + u * 512;
      const int d = (edst[e] >> shift) - blk * 128;
      const int s = (esrc[e] >> shift) - blk * 128;
      const int g = (s >> 3) ^ (d & 15);
      const int b = d * 128 + g * 8 + (s & 7);
      atomicAdd(&Mw[b >> 2], 1u << ((b & 3) * 8));
    }
  }

  // first MFMA: Y^T frags (lane = node myrow, ch = cf*16+lg*4+r)
  f32x4 acc1[8];
  #pragma unroll
  for (int cf = 0; cf < 8; ++cf) acc1[cf] = (f32x4){0.f, 0.f, 0.f, 0.f};
  #pragma unroll
  for (int ks = 0; ks < 4; ++ks) {
    const int swc = (ks * 4 + lg) ^ (lr & 7);
    #pragma unroll
    for (int cf = 0; cf < 8; ++cf) {
      bf16x8 wf = *(const bf16x8*)&BtYt[(cf * 16 + lr) * HDIM + swc * 8];
      acc1[cf] = __builtin_amdgcn_mfma_f32_16x16x32_bf16(wf, xf[ks], acc1[cf], 0, 0, 0);
    }
  }
  __syncthreads();                       // (3) W1 dead, M ready

  // spill Y^T -> LDS over W1 space: Yt[ch][node], 8B-granule g=node>>2
  // swizzled g^=((ch&7)<<1); scalar ushort writes (~2-way conflicts)
  ushort* Yt = BtYt;
  #pragma unroll
  for (int cf = 0; cf < 8; ++cf) {
    #pragma unroll
    for (int r = 0; r < 4; ++r) {
      const int ch = cf * 16 + lg * 4 + r;
      const int g = (myrow >> 2) ^ ((ch & 7) << 1);
      Yt[ch * HDIM + g * 4 + (myrow & 3)] = f2bf(acc1[cf][r]);
    }
  }
  __syncthreads();                       // (4) Y^T ready

  // second MFMA: H^T = Y^T @ (I+M)^T ; A from Yt (contig swizzled rows),
  // B from M rows (u8 -> bf16, conflict-free via granule XOR)
  const uchar* Mu8 = (const uchar*)AtM;
  f32x4 acc2[8];
  #pragma unroll
  for (int cf = 0; cf < 8; ++cf) acc2[cf] = (f32x4){0.f, 0.f, 0.f, 0.f};
  #pragma unroll
  for (int ks = 0; ks < 4; ++ks) {
    const int gm = (ks * 4 + lg) ^ (myrow & 15);
    uint2 mw = *(const uint2*)&Mu8[myrow * 128 + gm * 8];
    bf16x8 bfr;
    #pragma unroll
    for (int j = 0; j < 4; ++j) {
      bfr[j]     = (short)f2bf((float)((mw.x >> (8 * j)) & 0xFFu));
      bfr[j + 4] = (short)f2bf((float)((mw.y >> (8 * j)) & 0xFFu));
    }
    #pragma unroll
    for (int cf = 0; cf < 8; ++cf) {
      const int ch = cf * 16 + lr;
      const int g0 = (ks * 8 + lg * 2) ^ ((ch & 7) << 1);
      bf16x8 afr = *(const bf16x8*)&Yt[ch * HDIM + g0 * 4];
      acc2[cf] = __builtin_amdgcn_mfma_f32_16x16x32_bf16(afr, bfr, acc2[cf], 0, 0, 0);
    }
  }

  // epilogue: lane = dst row myrow, 4 consecutive ch per frag
  const size_t grow = blkRow0 + myrow;
  #pragma unroll
  for (int cf = 0; cf < 8; ++cf) {
    const int c0 = cf * 16 + lg * 4;
    float y[4];
    #pragma unroll
    for (int r = 0; r < 4; ++r) y[r] = acc2[cf][r] + biasL[c0 + r];
    ushort4 st;
    st.x = f2bf(y[0]); st.y = f2bf(y[1]); st.z = f2bf(y[2]); st.w = f2bf(y[3]);
    *(ushort4*)&out[grow * HDIM + c0] = st;
    colstat4(sred, c0, y, lr);
  }
  __syncthreads();
  if (t < 2 * HDIM) atomicAdd(&outStats[t], sred[t]);
}

// x' = haar(act(h)) ; emb[g] ; embd col-stats. bf16 in/out, emb f32.
__global__ __launch_bounds__(256, 4)
void k_pool(const ushort* __restrict__ hin, ushort* __restrict__ xout,
            float* __restrict__ emb, int layer, int npg_in,
            const float* __restrict__ actStats, const float* __restrict__ actG,
            const float* __restrict__ actB, float act_inv_n,
            float* __restrict__ embStats) {
  __shared__ float aA[HDIM], aC[HDIM];
  __shared__ float red[256];
  const int t = threadIdx.x;
  const int g = blockIdx.x;
  bn_coefs(actStats, actG, actB, act_inv_n, aA, aC, t);
  __syncthreads();
  const int c = t & 127;
  const int ph = t >> 7;
  const int npg_out = npg_in >> 1;
  const ushort* hb = hin + (size_t)g * npg_in * HDIM;
  ushort* xb = xout + (size_t)g * npg_out * HDIM;
  const float a = aA[c], cc = aC[c];
  float es = 0.f;
  for (int p = ph; p < npg_out; p += 2) {
    float v0 = fmaxf(fmaf(a, bf2f(hb[(2 * p    ) * HDIM + c]), cc), 0.f);
    float v1 = fmaxf(fmaf(a, bf2f(hb[(2 * p + 1) * HDIM + c]), cc), 0.f);
    float xv = (v0 + v1) * INV_SQRT2;
    xb[p * HDIM + c] = f2bf(xv);
    es += xv;
  }
  red[t] = es;
  __syncthreads();
  if (t < HDIM) {
    float e = red[t] + red[t + HDIM];
    emb[(size_t)g * 384 + layer * HDIM + t] = e;
    atomicAdd(&embStats[t], e);
    atomicAdd(&embStats[HDIM + t], e * e);
  }
}

__global__ __launch_bounds__(128, 8)
void k_final(const float* __restrict__ emb,
             const float* __restrict__ se0, const float* __restrict__ se1,
             const float* __restrict__ se2,
             const float* __restrict__ bneG, const float* __restrict__ bneB,
             const float* __restrict__ linW, const float* __restrict__ linB,
             float* __restrict__ outp) {
  __shared__ float ev[384];
  __shared__ float eA[384], eC[384];
  const int t = threadIdx.x;
  const int g = blockIdx.x;
  if (t < 128) {
    const float* se[3] = {se0, se1, se2};
    const float inv_n = 1.f / (float)G_GRAPHS;
    #pragma unroll
    for (int l = 0; l < 3; ++l) {
      float s  = se[l][t];
      float ss = se[l][128 + t];
      float m  = s * inv_n;
      float var = fmaxf(ss * inv_n - m * m, 0.f);
      float a = bneG[l * 128 + t] * rsqrtf(var + BN_EPS);
      eA[l * 128 + t] = a;
      eC[l * 128 + t] = bneB[l * 128 + t] - m * a;
    }
  }
  __syncthreads();
  for (int j = t; j < 384; j += 128)
    ev[j] = fmaxf(fmaf(eA[j], emb[(size_t)g * 384 + j], eC[j]), 0.f);
  __syncthreads();
  if (t < 10) {
    float acc = linB[t];
    #pragma unroll 8
    for (int j = 0; j < 384; ++j) acc += ev[j] * linW[j * 10 + t];
    outp[g * 10 + t] = acc;
  }
}

extern "C" void kernel_launch(void* const* d_in, const int* in_sizes, int n_in,
                              void* d_out, int out_size, void* d_ws, size_t ws_size,
                              hipStream_t stream) {
  const float* x           = (const float*)d_in[0];
  const int*   ei          = (const int*)  d_in[1];
  const float* lin_start_w = (const float*)d_in[2];
  const float* lin_start_b = (const float*)d_in[3];
  const float* bn_start_g  = (const float*)d_in[4];
  const float* bn_start_b  = (const float*)d_in[5];
  const float* conv_w1     = (const float*)d_in[6];
  const float* conv_b1     = (const float*)d_in[7];
  const float* conv_bn_g   = (const float*)d_in[8];
  const float* conv_bn_b   = (const float*)d_in[9];
  const float* conv_w2     = (const float*)d_in[10];
  const float* conv_b2     = (const float*)d_in[11];
  const float* bn_g        = (const float*)d_in[12];
  const float* bn_b        = (const float*)d_in[13];
  const float* bne_g       = (const float*)d_in[14];
  const float* bne_b       = (const float*)d_in[15];
  const float* lin_w       = (const float*)d_in[16];
  const float* lin_b       = (const float*)d_in[17];
  float* outp = (float*)d_out;

  const size_t NH = (size_t)N_NODES * HDIM;
  float*  stats = (float*)d_ws;                       // 10 slots * 256
  float*  emb   = stats + 10 * 256;                   // G * 384
  ushort* wt    = (ushort*)(emb + (size_t)G_GRAPHS * 384);  // 7 * 128 * 128
  ushort* bufA  = wt + 7 * HDIM * HDIM;
  ushort* bufB  = bufA + NH;

  hipMemsetAsync(stats, 0, 10 * 256 * sizeof(float), stream);

  const int* esrc = ei;
  const int* edst = ei + E_EDGES;

  k_prep<<<7, 256, 0, stream>>>(lin_start_w, conv_w1, conv_w2, wt);

  // y0 = x @ lin_start_w + b (stats -> slot 0)
  k_mm<0, 1><<<N_NODES / 128, 512, 0, stream>>>(
      x, bufA, wt, lin_start_b, nullptr, nullptr, nullptr, 0.f, stats);

  ushort* cur = bufA;
  ushort* alt = bufB;
  for (int i = 0; i < 3; ++i) {
    const int n = N_NODES >> i;
    const float inv_n = 1.f / (float)n;
    float* s1 = stats + (1 + 3 * i) * 256;
    float* s2 = stats + (2 + 3 * i) * 256;
    float* se = stats + (3 + 3 * i) * 256;
    const ushort* wt1 = wt + (size_t)(1 + i) * HDIM * HDIM;
    const ushort* wt2 = wt + (size_t)(4 + i) * HDIM * HDIM;

    // h1 = (I+M) @ (act(x) @ w1) + b1  (stats -> s1)
    if (i == 0)
      k_gin<4, 1><<<n / 128, 512, 0, stream>>>(cur, alt, esrc, edst, 0, wt1,
          conv_b1 + i * HDIM, stats, bn_start_g, bn_start_b,
          1.f / (float)N_NODES, s1);
    else if (i == 1)
      k_gin<8, 0><<<n / 128, 512, 0, stream>>>(cur, alt, esrc, edst, 1, wt1,
          conv_b1 + i * HDIM, nullptr, nullptr, nullptr, 0.f, s1);
    else
      k_gin<16, 0><<<n / 128, 512, 0, stream>>>(cur, alt, esrc, edst, 2, wt1,
          conv_b1 + i * HDIM, nullptr, nullptr, nullptr, 0.f, s1);

    // h2 = relu(bn(h1)) @ w2 + b2 (stats -> s2)
    k_mm<1, 0><<<n / 128, 512, 0, stream>>>(
        alt, cur, wt2, conv_b2 + i * HDIM,
        s1, conv_bn_g + i * HDIM, conv_bn_b + i * HDIM, inv_n, s2);
    // x' = haar(relu(bn(h2))) ; emb col i ; embd stats -> se
    k_pool<<<G_GRAPHS, 256, 0, stream>>>(
        cur, alt, emb, i, NPG0 >> i,
        s2, bn_g + i * HDIM, bn_b + i * HDIM, inv_n, se);

    ushort* tmp = cur; cur = alt; alt = tmp;
  }

  k_final<<<G_GRAPHS, 128, 0, stream>>>(
      emb, stats + 3 * 256, stats + 6 * 256, stats + 9 * 256,
      bne_g, bne_b, lin_w, lin_b, outp);
}

// Round 7
// 337.646 us; speedup vs baseline: 1.4399x; 1.1617x over previous
//
#include <hip/hip_runtime.h>

#define N_NODES  131072
#define G_GRAPHS 1024
#define NPG0     128
#define HDIM     128
#define E_EDGES  2097152
#define EPG      2048
#define BN_EPS   1e-5f
#define INV_SQRT2 0.70710678118654752440f

typedef __attribute__((ext_vector_type(8))) short bf16x8;
typedef __attribute__((ext_vector_type(4))) float f32x4;

__device__ __forceinline__ float bf2f(ushort u) {
  union { unsigned int i; float f; } v; v.i = ((unsigned int)u) << 16; return v.f;
}
__device__ __forceinline__ ushort f2bf(float f) {
  union { float f; unsigned int i; } v; v.f = f;
  unsigned int u = v.i;
  return (ushort)((u + 0x7FFFu + ((u >> 16) & 1u)) >> 16);
}

// async global->LDS DMA, 16B per lane (wave-uniform LDS base + lane*16)
__device__ __forceinline__ void ldsdma16(const void* g, void* l) {
  __builtin_amdgcn_global_load_lds(
      (const __attribute__((address_space(1))) void*)g,
      (__attribute__((address_space(3))) void*)l, 16, 0, 0);
}

__device__ __forceinline__ void bn_coefs(const float* __restrict__ stats,
                                         const float* __restrict__ gamma,
                                         const float* __restrict__ beta,
                                         float inv_n, float* cA, float* cC, int t) {
  if (t < HDIM) {
    float s  = stats[t];
    float ss = stats[HDIM + t];
    float m  = s * inv_n;
    float var = fmaxf(ss * inv_n - m * m, 0.f);
    float a = gamma[t] * rsqrtf(var + BN_EPS);
    cA[t] = a;
    cC[t] = beta[t] - m * a;
  }
}

// Store one ushort4 (4 consecutive channels c0=cf*16+lg*4 of row myrow) into the
// bf16 y-tile buffer, granule(8B)-XOR-swizzled: 2-way worst-case bank aliasing.
__device__ __forceinline__ void ybuf_store4(ushort* __restrict__ ybuf, int myrow,
                                            int cf, int lg, ushort4 st) {
  const int gp = ((cf ^ (myrow & 7)) << 2) | lg;
  *(ushort4*)&ybuf[myrow * HDIM + gp * 4] = st;
}

// Column sum/sumsq of the swizzled bf16 y-tile [128 rows][128 ch] -> sred[256].
// 512 threads: thread = (row-quarter, channel); 32 b16 reads each, ~2-way banks.
__device__ __forceinline__ void stats_pass(const ushort* __restrict__ ybuf,
                                           float* __restrict__ sred, int t) {
  const int ch  = t & 127;
  const int r0  = (t >> 7) * 32;
  const int cfh = ch >> 4, lgh = (ch >> 2) & 3, off = ch & 3;
  float s = 0.f, q = 0.f;
  #pragma unroll
  for (int i = 0; i < 32; ++i) {
    const int r  = r0 + i;
    const int gp = ((cfh ^ (r & 7)) << 2) | lgh;
    const float v = bf2f(ybuf[r * HDIM + gp * 4 + off]);
    s += v; q += v * v;
  }
  atomicAdd(&sred[ch], s);
  atomicAdd(&sred[HDIM + ch], q);
}

// Transpose + bf16-convert the 7 weight matrices into wt[m][n][k].
__global__ __launch_bounds__(256, 2)
void k_prep(const float* __restrict__ w_lin_start, const float* __restrict__ w_conv1,
            const float* __restrict__ w_conv2, ushort* __restrict__ wt) {
  __shared__ ushort T[128 * 136];
  const int m = blockIdx.x;
  const int t = threadIdx.x;
  const float* W = (m == 0) ? w_lin_start
                 : (m <= 3) ? w_conv1 + (size_t)(m - 1) * HDIM * HDIM
                            : w_conv2 + (size_t)(m - 4) * HDIM * HDIM;
  for (int it = 0; it < 64; ++it) {
    int idx = it * 256 + t;          // W row-major [k][n]
    int k = idx >> 7, n = idx & 127;
    T[k * 136 + n] = f2bf(W[idx]);
  }
  __syncthreads();
  ushort* o = wt + (size_t)m * HDIM * HDIM;  // [n][k]
  for (int it = 0; it < 64; ++it) {
    int idx = it * 256 + t;
    int n = idx >> 7, k = idx & 127;
    o[idx] = T[k * 136 + n];
  }
}

// GEMM: out = (act(in) @ W) + bias ; col stats -> outStats.
// 512 thr = 8 waves x 16 rows. A-fragments straight from global (rows L2/L3
// resident, each element read once per block); W via LDS-DMA. Epilogue: bf16
// y-tile into Bt's dead space, then stats_pass (replaces shuffle-storm).
template <int ACT, int FP32IN>
__global__ __launch_bounds__(512, FP32IN ? 4 : 8)
void k_mm(const void* __restrict__ in_v, ushort* __restrict__ out,
          const ushort* __restrict__ Wt, const float* __restrict__ bias,
          const float* __restrict__ actStats, const float* __restrict__ actG,
          const float* __restrict__ actB, float act_inv_n,
          float* __restrict__ outStats) {
  __shared__ ushort Bt[HDIM * HDIM];   // 32 KB: W^T -> ybuf
  __shared__ float biasL[HDIM], sred[2 * HDIM], aA[HDIM], aC[HDIM];
  const int t = threadIdx.x;
  const int lane = t & 63;
  const int w = t >> 6;
  const int lr = lane & 15;
  const int lg = lane >> 4;
  const int myrow = w * 16 + lr;

  // W -> Bt via DMA (pre-swizzled source, linear LDS dest)
  #pragma unroll
  for (int is = 0; is < 4; ++is) {
    const int col = is * 32 + w * 4 + (lane >> 4);
    const int gsc = (lane & 15) ^ (col & 7);
    ldsdma16(Wt + (size_t)col * HDIM + gsc * 8, &Bt[(is * 512 + w * 64) * 8]);
  }

  if (ACT) bn_coefs(actStats, actG, actB, act_inv_n, aA, aC, t);
  if (t < HDIM) biasL[t] = bias[t];
  if (t < 2 * HDIM) sred[t] = 0.f;
  __syncthreads();   // W ready; aA/aC ready

  // A-fragments direct from global
  const size_t blkRow0 = (size_t)blockIdx.x * 128;
  bf16x8 afr[4];
  if (FP32IN) {
    const float* inF = (const float*)in_v;
    #pragma unroll
    for (int ks = 0; ks < 4; ++ks) {
      const float* gp = inF + (blkRow0 + myrow) * HDIM + ks * 32 + lg * 8;
      float4 v0 = *(const float4*)gp;
      float4 v1 = *(const float4*)(gp + 4);
      afr[ks][0] = (short)f2bf(v0.x); afr[ks][1] = (short)f2bf(v0.y);
      afr[ks][2] = (short)f2bf(v0.z); afr[ks][3] = (short)f2bf(v0.w);
      afr[ks][4] = (short)f2bf(v1.x); afr[ks][5] = (short)f2bf(v1.y);
      afr[ks][6] = (short)f2bf(v1.z); afr[ks][7] = (short)f2bf(v1.w);
    }
  } else {
    const ushort* inB = (const ushort*)in_v;
    #pragma unroll
    for (int ks = 0; ks < 4; ++ks) {
      bf16x8 a = *(const bf16x8*)(inB + (blkRow0 + myrow) * HDIM + ks * 32 + lg * 8);
      if (ACT) {
        const int k0 = ks * 32 + lg * 8;
        #pragma unroll
        for (int j = 0; j < 8; ++j) {
          float f = fmaxf(fmaf(aA[k0 + j], bf2f((ushort)a[j]), aC[k0 + j]), 0.f);
          a[j] = (short)f2bf(f);
        }
      }
      afr[ks] = a;
    }
  }

  f32x4 acc[8];
  #pragma unroll
  for (int cf = 0; cf < 8; ++cf) acc[cf] = (f32x4){0.f, 0.f, 0.f, 0.f};
  #pragma unroll
  for (int ks = 0; ks < 4; ++ks) {
    const int swc = (ks * 4 + lg) ^ (lr & 7);
    #pragma unroll
    for (int cf = 0; cf < 8; ++cf) {
      bf16x8 bfr = *(const bf16x8*)&Bt[(cf * 16 + lr) * HDIM + swc * 8];
      // swapped operands: D lane = input row, 4 consecutive ch per reg
      acc[cf] = __builtin_amdgcn_mfma_f32_16x16x32_bf16(bfr, afr[ks], acc[cf], 0, 0, 0);
    }
  }
  __syncthreads();   // Bt dead -> ybuf

  ushort* ybuf = Bt;
  const size_t grow = blkRow0 + myrow;
  #pragma unroll
  for (int cf = 0; cf < 8; ++cf) {
    const int c0 = cf * 16 + lg * 4;
    float y[4];
    #pragma unroll
    for (int r = 0; r < 4; ++r) y[r] = acc[cf][r] + biasL[c0 + r];
    ushort4 st;
    st.x = f2bf(y[0]); st.y = f2bf(y[1]); st.z = f2bf(y[2]); st.w = f2bf(y[3]);
    *(ushort4*)&out[grow * HDIM + c0] = st;
    ybuf_store4(ybuf, myrow, cf, lg, st);
  }
  __syncthreads();   // ybuf ready
  stats_pass(ybuf, sred, t);
  __syncthreads();
  if (t < 2 * HDIM) atomicAdd(&outStats[t], sred[t]);
}

// Fused GIN front: out = (I+M) @ (act(x) @ W1) + b1, M = edge multiplicity
// (block-diag; 128-row tile covers whole graphs). Two chained MFMAs; M built
// as u8 counts in dedicated 16KB LDS; xf direct from global. BtYt: W1 -> Y^T
// -> ybuf. ~52 KB LDS -> 3 blocks/CU at <=64 VGPR.
template <int EPT, int ACT>
__global__ __launch_bounds__(512, 8)
void k_gin(const ushort* __restrict__ xin, ushort* __restrict__ out,
           const int* __restrict__ esrc, const int* __restrict__ edst,
           int shift, const ushort* __restrict__ Wt,
           const float* __restrict__ bias,
           const float* __restrict__ actStats, const float* __restrict__ actG,
           const float* __restrict__ actB, float act_inv_n,
           float* __restrict__ outStats) {
  __shared__ ushort BtYt[HDIM * HDIM];  // 32 KB: W1 -> Y^T -> ybuf
  __shared__ uchar  Msm[128 * 128];     // 16 KB: u8 multiplicities
  __shared__ float biasL[HDIM], sred[2 * HDIM], aA[HDIM], aC[HDIM];
  const int t = threadIdx.x;
  const int lane = t & 63;
  const int w = t >> 6;
  const int lr = lane & 15;
  const int lg = lane >> 4;
  const int blk = blockIdx.x;
  const int myrow = w * 16 + lr;

  // W1 -> BtYt via DMA
  #pragma unroll
  for (int is = 0; is < 4; ++is) {
    const int col = is * 32 + w * 4 + (lane >> 4);
    const int gsc = (lane & 15) ^ (col & 7);
    ldsdma16(Wt + (size_t)col * HDIM + gsc * 8, &BtYt[(is * 512 + w * 64) * 8]);
  }

  // zero M
  uint* Mw = (uint*)Msm;
  #pragma unroll
  for (int i = 0; i < 8; ++i) Mw[i * 512 + t] = 0u;

  if (ACT) bn_coefs(actStats, actG, actB, act_inv_n, aA, aC, t);
  if (t < HDIM) biasL[t] = bias[t];
  if (t < 2 * HDIM) sred[t] = 0.f;
  __syncthreads();   // W1 ready, M zeroed, aA/aC ready

  // xf direct from global (+ACT in regs)
  const size_t blkRow0 = (size_t)blk * 128;
  const ushort* xg = xin + blkRow0 * HDIM;
  bf16x8 xf[4];
  #pragma unroll
  for (int ks = 0; ks < 4; ++ks) {
    bf16x8 a = *(const bf16x8*)(xg + (size_t)myrow * HDIM + ks * 32 + lg * 8);
    if (ACT) {
      const int k0 = ks * 32 + lg * 8;
      #pragma unroll
      for (int j = 0; j < 8; ++j) {
        float f = fmaxf(fmaf(aA[k0 + j], bf2f((ushort)a[j]), aC[k0 + j]), 0.f);
        a[j] = (short)f2bf(f);
      }
    }
    xf[ks] = a;
  }

  // build M: diag (self) + edge multiplicities, src-granule XOR swizzle
  if (t < 128) {
    const int g = (t >> 3) ^ (t & 15);
    const int b = t * 128 + g * 8 + (t & 7);
    atomicAdd(&Mw[b >> 2], 1u << ((b & 3) * 8));
  }
  {
    const int ebase = blk * (EPT * 512);
    #pragma unroll
    for (int u = 0; u < EPT; ++u) {
      const int e = ebase + t + u * 512;
      const int d = (edst[e] >> shift) - blk * 128;
      const int s = (esrc[e] >> shift) - blk * 128;
      const int g = (s >> 3) ^ (d & 15);
      const int b = d * 128 + g * 8 + (s & 7);
      atomicAdd(&Mw[b >> 2], 1u << ((b & 3) * 8));
    }
  }

  // MFMA1: Y = act(x) @ W1 (lane = node myrow, ch = cf*16+lg*4+r)
  f32x4 acc1[8];
  #pragma unroll
  for (int cf = 0; cf < 8; ++cf) acc1[cf] = (f32x4){0.f, 0.f, 0.f, 0.f};
  #pragma unroll
  for (int ks = 0; ks < 4; ++ks) {
    const int swc = (ks * 4 + lg) ^ (lr & 7);
    #pragma unroll
    for (int cf = 0; cf < 8; ++cf) {
      bf16x8 wf = *(const bf16x8*)&BtYt[(cf * 16 + lr) * HDIM + swc * 8];
      acc1[cf] = __builtin_amdgcn_mfma_f32_16x16x32_bf16(wf, xf[ks], acc1[cf], 0, 0, 0);
    }
  }
  __syncthreads();   // W1 dead, M complete

  // spill Y^T -> BtYt: Yt[ch][node], granule-swizzled
  ushort* Yt = BtYt;
  #pragma unroll
  for (int cf = 0; cf < 8; ++cf) {
    #pragma unroll
    for (int r = 0; r < 4; ++r) {
      const int ch = cf * 16 + lg * 4 + r;
      const int g = (myrow >> 2) ^ ((ch & 7) << 1);
      Yt[ch * HDIM + g * 4 + (myrow & 3)] = f2bf(acc1[cf][r]);
    }
  }
  __syncthreads();   // Y^T ready

  // MFMA2: H^T = Y^T @ (I+M)^T
  const uchar* Mu8 = (const uchar*)Msm;
  f32x4 acc2[8];
  #pragma unroll
  for (int cf = 0; cf < 8; ++cf) acc2[cf] = (f32x4){0.f, 0.f, 0.f, 0.f};
  #pragma unroll
  for (int ks = 0; ks < 4; ++ks) {
    const int gm = (ks * 4 + lg) ^ (myrow & 15);
    uint2 mw = *(const uint2*)&Mu8[myrow * 128 + gm * 8];
    bf16x8 bfr;
    #pragma unroll
    for (int j = 0; j < 4; ++j) {
      bfr[j]     = (short)f2bf((float)((mw.x >> (8 * j)) & 0xFFu));
      bfr[j + 4] = (short)f2bf((float)((mw.y >> (8 * j)) & 0xFFu));
    }
    #pragma unroll
    for (int cf = 0; cf < 8; ++cf) {
      const int ch = cf * 16 + lr;
      const int g0 = (ks * 8 + lg * 2) ^ ((ch & 7) << 1);
      bf16x8 afr = *(const bf16x8*)&Yt[ch * HDIM + g0 * 4];
      acc2[cf] = __builtin_amdgcn_mfma_f32_16x16x32_bf16(afr, bfr, acc2[cf], 0, 0, 0);
    }
  }
  __syncthreads();   // Yt dead -> ybuf

  // epilogue: lane = dst row myrow, 4 consecutive ch per frag
  ushort* ybuf = BtYt;
  const size_t grow = blkRow0 + myrow;
  #pragma unroll
  for (int cf = 0; cf < 8; ++cf) {
    const int c0 = cf * 16 + lg * 4;
    float y[4];
    #pragma unroll
    for (int r = 0; r < 4; ++r) y[r] = acc2[cf][r] + biasL[c0 + r];
    ushort4 st;
    st.x = f2bf(y[0]); st.y = f2bf(y[1]); st.z = f2bf(y[2]); st.w = f2bf(y[3]);
    *(ushort4*)&out[grow * HDIM + c0] = st;
    ybuf_store4(ybuf, myrow, cf, lg, st);
  }
  __syncthreads();   // ybuf ready
  stats_pass(ybuf, sred, t);
  __syncthreads();
  if (t < 2 * HDIM) atomicAdd(&outStats[t], sred[t]);
}

// x' = haar(act(h)) ; emb[g] ; embd col-stats. bf16 in/out, emb f32.
__global__ __launch_bounds__(256, 4)
void k_pool(const ushort* __restrict__ hin, ushort* __restrict__ xout,
            float* __restrict__ emb, int layer, int npg_in,
            const float* __restrict__ actStats, const float* __restrict__ actG,
            const float* __restrict__ actB, float act_inv_n,
            float* __restrict__ embStats) {
  __shared__ float aA[HDIM], aC[HDIM];
  __shared__ float red[256];
  const int t = threadIdx.x;
  const int g = blockIdx.x;
  bn_coefs(actStats, actG, actB, act_inv_n, aA, aC, t);
  __syncthreads();
  const int c = t & 127;
  const int ph = t >> 7;
  const int npg_out = npg_in >> 1;
  const ushort* hb = hin + (size_t)g * npg_in * HDIM;
  ushort* xb = xout + (size_t)g * npg_out * HDIM;
  const float a = aA[c], cc = aC[c];
  float es = 0.f;
  for (int p = ph; p < npg_out; p += 2) {
    float v0 = fmaxf(fmaf(a, bf2f(hb[(2 * p    ) * HDIM + c]), cc), 0.f);
    float v1 = fmaxf(fmaf(a, bf2f(hb[(2 * p + 1) * HDIM + c]), cc), 0.f);
    float xv = (v0 + v1) * INV_SQRT2;
    xb[p * HDIM + c] = f2bf(xv);
    es += xv;
  }
  red[t] = es;
  __syncthreads();
  if (t < HDIM) {
    float e = red[t] + red[t + HDIM];
    emb[(size_t)g * 384 + layer * HDIM + t] = e;
    atomicAdd(&embStats[t], e);
    atomicAdd(&embStats[HDIM + t], e * e);
  }
}

__global__ __launch_bounds__(128, 8)
void k_final(const float* __restrict__ emb,
             const float* __restrict__ se0, const float* __restrict__ se1,
             const float* __restrict__ se2,
             const float* __restrict__ bneG, const float* __restrict__ bneB,
             const float* __restrict__ linW, const float* __restrict__ linB,
             float* __restrict__ outp) {
  __shared__ float ev[384];
  __shared__ float eA[384], eC[384];
  const int t = threadIdx.x;
  const int g = blockIdx.x;
  if (t < 128) {
    const float* se[3] = {se0, se1, se2};
    const float inv_n = 1.f / (float)G_GRAPHS;
    #pragma unroll
    for (int l = 0; l < 3; ++l) {
      float s  = se[l][t];
      float ss = se[l][128 + t];
      float m  = s * inv_n;
      float var = fmaxf(ss * inv_n - m * m, 0.f);
      float a = bneG[l * 128 + t] * rsqrtf(var + BN_EPS);
      eA[l * 128 + t] = a;
      eC[l * 128 + t] = bneB[l * 128 + t] - m * a;
    }
  }
  __syncthreads();
  for (int j = t; j < 384; j += 128)
    ev[j] = fmaxf(fmaf(eA[j], emb[(size_t)g * 384 + j], eC[j]), 0.f);
  __syncthreads();
  if (t < 10) {
    float acc = linB[t];
    #pragma unroll 8
    for (int j = 0; j < 384; ++j) acc += ev[j] * linW[j * 10 + t];
    outp[g * 10 + t] = acc;
  }
}

extern "C" void kernel_launch(void* const* d_in, const int* in_sizes, int n_in,
                              void* d_out, int out_size, void* d_ws, size_t ws_size,
                              hipStream_t stream) {
  const float* x           = (const float*)d_in[0];
  const int*   ei          = (const int*)  d_in[1];
  const float* lin_start_w = (const float*)d_in[2];
  const float* lin_start_b = (const float*)d_in[3];
  const float* bn_start_g  = (const float*)d_in[4];
  const float* bn_start_b  = (const float*)d_in[5];
  const float* conv_w1     = (const float*)d_in[6];
  const float* conv_b1     = (const float*)d_in[7];
  const float* conv_bn_g   = (const float*)d_in[8];
  const float* conv_bn_b   = (const float*)d_in[9];
  const float* conv_w2     = (const float*)d_in[10];
  const float* conv_b2     = (const float*)d_in[11];
  const float* bn_g        = (const float*)d_in[12];
  const float* bn_b        = (const float*)d_in[13];
  const float* bne_g       = (const float*)d_in[14];
  const float* bne_b       = (const float*)d_in[15];
  const float* lin_w       = (const float*)d_in[16];
  const float* lin_b       = (const float*)d_in[17];
  float* outp = (float*)d_out;

  const size_t NH = (size_t)N_NODES * HDIM;
  float*  stats = (float*)d_ws;                       // 10 slots * 256
  float*  emb   = stats + 10 * 256;                   // G * 384
  ushort* wt    = (ushort*)(emb + (size_t)G_GRAPHS * 384);  // 7 * 128 * 128
  ushort* bufA  = wt + 7 * HDIM * HDIM;
  ushort* bufB  = bufA + NH;

  hipMemsetAsync(stats, 0, 10 * 256 * sizeof(float), stream);

  const int* esrc = ei;
  const int* edst = ei + E_EDGES;

  k_prep<<<7, 256, 0, stream>>>(lin_start_w, conv_w1, conv_w2, wt);

  // y0 = x @ lin_start_w + b (stats -> slot 0)
  k_mm<0, 1><<<N_NODES / 128, 512, 0, stream>>>(
      x, bufA, wt, lin_start_b, nullptr, nullptr, nullptr, 0.f, stats);

  ushort* cur = bufA;
  ushort* alt = bufB;
  for (int i = 0; i < 3; ++i) {
    const int n = N_NODES >> i;
    const float inv_n = 1.f / (float)n;
    float* s1 = stats + (1 + 3 * i) * 256;
    float* s2 = stats + (2 + 3 * i) * 256;
    float* se = stats + (3 + 3 * i) * 256;
    const ushort* wt1 = wt + (size_t)(1 + i) * HDIM * HDIM;
    const ushort* wt2 = wt + (size_t)(4 + i) * HDIM * HDIM;

    // h1 = (I+M) @ (act(x) @ w1) + b1  (stats -> s1)
    if (i == 0)
      k_gin<4, 1><<<n / 128, 512, 0, stream>>>(cur, alt, esrc, edst, 0, wt1,
          conv_b1 + i * HDIM, stats, bn_start_g, bn_start_b,
          1.f / (float)N_NODES, s1);
    else if (i == 1)
      k_gin<8, 0><<<n / 128, 512, 0, stream>>>(cur, alt, esrc, edst, 1, wt1,
          conv_b1 + i * HDIM, nullptr, nullptr, nullptr, 0.f, s1);
    else
      k_gin<16, 0><<<n / 128, 512, 0, stream>>>(cur, alt, esrc, edst, 2, wt1,
          conv_b1 + i * HDIM, nullptr, nullptr, nullptr, 0.f, s1);

    // h2 = relu(bn(h1)) @ w2 + b2 (stats -> s2)
    k_mm<1, 0><<<n / 128, 512, 0, stream>>>(
        alt, cur, wt2, conv_b2 + i * HDIM,
        s1, conv_bn_g + i * HDIM, conv_bn_b + i * HDIM, inv_n, s2);
    // x' = haar(relu(bn(h2))) ; emb col i ; embd stats -> se
    k_pool<<<G_GRAPHS, 256, 0, stream>>>(
        cur, alt, emb, i, NPG0 >> i,
        s2, bn_g + i * HDIM, bn_b + i * HDIM, inv_n, se);

    ushort* tmp = cur; cur = alt; alt = tmp;
  }

  k_final<<<G_GRAPHS, 128, 0, stream>>>(
      emb, stats + 3 * 256, stats + 6 * 256, stats + 9 * 256,
      bne_g, bne_b, lin_w, lin_b, outp);
}